// Round 6
// baseline (2074.411 us; speedup 1.0000x reference)
//
#include <hip/hip_runtime.h>
#include <math.h>

// Persistent-pipeline geometry: 2-row x 64-col strips, 4x66 halo patch
#define PSTR  40              // fp16 cell stride: 80 B
#define NCELL 264             // 4 * 66 patch cells
#define XBH   (NCELL * PSTR)  // halfs per patch buffer

typedef _Float16 half8 __attribute__((ext_vector_type(8)));
typedef float    f32x4 __attribute__((ext_vector_type(4)));

__device__ __forceinline__ float fast_tanh(float v) {
    float e = __expf(2.f * v);
    return 1.f - 2.f / (e + 1.f);
}
__device__ __forceinline__ float hsig(float v) {
    return fminf(fmaxf(0.2f * v + 0.5f, 0.f), 1.f);
}

// Pack weights: Wcx[tap][n][ci<32] from Wx[tap][ci][n]; Wch[tap][n][ci] from Wh[tap][ci][n]
__global__ void prep_w(const float* __restrict__ Wx, const float* __restrict__ Wh,
                       _Float16* __restrict__ Wcx, _Float16* __restrict__ Wch) {
    const int k = blockIdx.x;      // 0..575 = tap*64 + ci
    const int n = threadIdx.x;     // 0..127
    const int tap = k >> 6, ci = k & 63;
    if (ci < 32) Wcx[(tap * 128 + n) * 32 + ci]        = (_Float16)Wx[(tap * 32 + ci) * 128 + n];
    else         Wch[(tap * 128 + n) * 32 + (ci - 32)] = (_Float16)Wh[(tap * 32 + (ci - 32)) * 128 + n];
}

// Persistent pipelined kernel: one block per (b, 2-row strip), 256 blocks co-resident
// (cooperative launch for residency guarantee only — NO grid.sync). Each block runs
// all 16 timesteps; c stays in registers; h exchanged via double-buffered global with
// per-strip flags (flag[b][s] = number of completed steps). Block waits only on its
// 2 vertical neighbors, so the grid pipelines diagonally instead of barriering.
// Wave (chg=w&1, seg=w>>1): 32 px (2 m-tiles) x 64 gate-ch. px = (seg*2+mt)*16+quad*4+r
// within strip (row = px>>6, col = px&63); f = chg*16+l15; nt = gate.
__global__ __launch_bounds__(512, 2)
void convlstm_pipe(const float* __restrict__ x, const _Float16* __restrict__ Wcx,
                   const _Float16* __restrict__ Wch, const float* __restrict__ bias,
                   const float* __restrict__ gamma_, const float* __restrict__ beta_,
                   const float* __restrict__ mmean, const float* __restrict__ mvar,
                   _Float16* __restrict__ h0, _Float16* __restrict__ h1,
                   int* __restrict__ flags, float* __restrict__ out)
{
    __shared__ _Float16 xb[2 * XBH];   // 42.2 KB: double-buffered 4x66 x-patch
    __shared__ _Float16 hp[XBH];       // 21.1 KB: 4x66 h-patch

    const int tid  = threadIdx.x;      // 0..511
    const int lane = tid & 63;
    const int w    = tid >> 6;         // 0..7
    const int l15  = lane & 15, quad = lane >> 4;
    const int chg  = w & 1, seg = w >> 1;
    const int b = blockIdx.x, s = blockIdx.y;
    const int y0 = s * 2;

    // ---- constants ----
    const int f = chg * 16 + l15;
    float bi[4];
    #pragma unroll
    for (int nt = 0; nt < 4; ++nt) bi[nt] = bias[nt * 32 + f];
    const float inv = gamma_[f] * rsqrtf(mvar[f] + 1e-3f);
    const float bnb = beta_[f] - mmean[f] * inv;

    // A-frag LDS bases: lane row px = (seg*2+mt)*16 + l15 -> patch cell (row)*66+(col)
    int qb[2];
    #pragma unroll
    for (int mt = 0; mt < 2; ++mt) {
        const int p = (seg * 2 + mt) * 16 + l15;
        qb[mt] = ((p >> 6) * 66 + (p & 63)) * PSTR + quad * 8;
    }
    const _Float16* wbx = Wcx + (chg * 16 + l15) * 32 + quad * 8;
    const _Float16* wbh = Wch + (chg * 16 + l15) * 32 + quad * 8;

    const size_t hoff = (size_t)b * 4096 * 32;
    int* fb = flags + b * 32;

    f32x4 c0 = (f32x4){0.f, 0.f, 0.f, 0.f};   // cell state lives in registers
    f32x4 c1 = (f32x4){0.f, 0.f, 0.f, 0.f};

    // ---- prologue: stage x_0 into xb[0] ----
    {
        const float* xt = x + ((size_t)b * 16) * 4096 * 32;
        for (int i = tid; i < 1056; i += 512) {
            const int cell = i >> 2, q = i & 3;
            const int pr = (cell * 993) >> 16, pc = cell - pr * 66;
            const int gy = y0 - 1 + pr, gx = pc - 1;
            half8 hv = {0, 0, 0, 0, 0, 0, 0, 0};
            if ((unsigned)gy < 64u && (unsigned)gx < 64u) {
                const float* sp = xt + ((size_t)(gy * 64 + gx)) * 32 + q * 8;
                const float4 v0 = *(const float4*)sp;
                const float4 v1 = *(const float4*)(sp + 4);
                hv = (half8){(_Float16)v0.x, (_Float16)v0.y, (_Float16)v0.z, (_Float16)v0.w,
                             (_Float16)v1.x, (_Float16)v1.y, (_Float16)v1.z, (_Float16)v1.w};
            }
            *(half8*)&xb[cell * PSTR + q * 8] = hv;
        }
    }

    for (int t = 0; t < 16; ++t) {
        const int cur = t & 1;

        // ---- wait for vertical neighbors to finish step t-1 ----
        if (t > 0 && tid == 0) {
            if (s > 0)
                while (__hip_atomic_load(&fb[s - 1], __ATOMIC_RELAXED, __HIP_MEMORY_SCOPE_AGENT) < t)
                    __builtin_amdgcn_s_sleep(1);
            if (s < 31)
                while (__hip_atomic_load(&fb[s + 1], __ATOMIC_RELAXED, __HIP_MEMORY_SCOPE_AGENT) < t)
                    __builtin_amdgcn_s_sleep(1);
        }
        __syncthreads();                       // S0: flags observed; prev x-prefetch done

        // ---- stage h_{t-1} patch (acquire fence first: invalidate stale lines) ----
        if (t > 0) {
            __threadfence();
            const _Float16* hb = (cur ? h0 : h1) + hoff;   // h_{t-1} parity buffer
            for (int i = tid; i < 1056; i += 512) {
                const int cell = i >> 2, q = i & 3;
                const int pr = (cell * 993) >> 16, pc = cell - pr * 66;
                const int gy = y0 - 1 + pr, gx = pc - 1;
                half8 hv = {0, 0, 0, 0, 0, 0, 0, 0};
                if ((unsigned)gy < 64u && (unsigned)gx < 64u)
                    hv = *(const half8*)(hb + ((size_t)(gy * 64 + gx)) * 32 + q * 8);
                *(half8*)&hp[cell * PSTR + q * 8] = hv;
            }
        }
        // ---- prefetch x_{t+1} into the other buffer (overlaps h staging latency) ----
        if (t < 15) {
            const float* xt = x + ((size_t)b * 16 + t + 1) * 4096 * 32;
            _Float16* xd = &xb[(cur ^ 1) * XBH];
            for (int i = tid; i < 1056; i += 512) {
                const int cell = i >> 2, q = i & 3;
                const int pr = (cell * 993) >> 16, pc = cell - pr * 66;
                const int gy = y0 - 1 + pr, gx = pc - 1;
                half8 hv = {0, 0, 0, 0, 0, 0, 0, 0};
                if ((unsigned)gy < 64u && (unsigned)gx < 64u) {
                    const float* sp = xt + ((size_t)(gy * 64 + gx)) * 32 + q * 8;
                    const float4 v0 = *(const float4*)sp;
                    const float4 v1 = *(const float4*)(sp + 4);
                    hv = (half8){(_Float16)v0.x, (_Float16)v0.y, (_Float16)v0.z, (_Float16)v0.w,
                                 (_Float16)v1.x, (_Float16)v1.y, (_Float16)v1.z, (_Float16)v1.w};
                }
                *(half8*)&xd[cell * PSTR + q * 8] = hv;
            }
        }
        __syncthreads();                       // S1: hp + xb[cur] ready

        // ---- MFMA: x-conv + h-conv, 9 taps x 4 gates x 2 m-tiles ----
        f32x4 acc[2][4];
        #pragma unroll
        for (int mt = 0; mt < 2; ++mt)
            #pragma unroll
            for (int nt = 0; nt < 4; ++nt)
                acc[mt][nt] = (f32x4){bi[nt], bi[nt], bi[nt], bi[nt]};

        const _Float16* xp = &xb[cur * XBH];
        #pragma unroll
        for (int tap = 0; tap < 9; ++tap) {
            const int ky = tap / 3, kx = tap - ky * 3;
            const int toff = (ky * 66 + kx) * PSTR;
            const half8 a0 = *(const half8*)&xp[qb[0] + toff];
            const half8 a1 = *(const half8*)&xp[qb[1] + toff];
            #pragma unroll
            for (int nt = 0; nt < 4; ++nt) {
                const half8 bf = *(const half8*)(wbx + tap * 4096 + nt * 1024);
                acc[0][nt] = __builtin_amdgcn_mfma_f32_16x16x32_f16(a0, bf, acc[0][nt], 0, 0, 0);
                acc[1][nt] = __builtin_amdgcn_mfma_f32_16x16x32_f16(a1, bf, acc[1][nt], 0, 0, 0);
            }
        }
        if (t > 0) {
            #pragma unroll
            for (int tap = 0; tap < 9; ++tap) {
                const int ky = tap / 3, kx = tap - ky * 3;
                const int toff = (ky * 66 + kx) * PSTR;
                const half8 a0 = *(const half8*)&hp[qb[0] + toff];
                const half8 a1 = *(const half8*)&hp[qb[1] + toff];
                #pragma unroll
                for (int nt = 0; nt < 4; ++nt) {
                    const half8 bf = *(const half8*)(wbh + tap * 4096 + nt * 1024);
                    acc[0][nt] = __builtin_amdgcn_mfma_f32_16x16x32_f16(a0, bf, acc[0][nt], 0, 0, 0);
                    acc[1][nt] = __builtin_amdgcn_mfma_f32_16x16x32_f16(a1, bf, acc[1][nt], 0, 0, 0);
                }
            }
        }

        // ---- epilogue: LSTM (c in regs), write h_t + BN out_t ----
        _Float16* hc = (cur ? h1 : h0) + hoff;
        float* oq = out + ((size_t)b * 16 + t) * 4096 * 32;
        #pragma unroll
        for (int mt = 0; mt < 2; ++mt) {
            #pragma unroll
            for (int r = 0; r < 4; ++r) {
                const int px = (seg * 2 + mt) * 16 + quad * 4 + r;
                const int gy = y0 + (px >> 6), gx = px & 63;
                const float gi = acc[mt][0][r];
                const float gf = acc[mt][1][r];
                const float gc = acc[mt][2][r];
                const float go = acc[mt][3][r];
                const float co = mt ? c1[r] : c0[r];
                const float cn = hsig(gf) * co + hsig(gi) * fast_tanh(gc);
                const float hv = hsig(go) * fast_tanh(cn);
                if (mt) c1[r] = cn; else c0[r] = cn;
                const size_t pix = ((size_t)(gy * 64 + gx)) * 32 + f;
                if (t < 15) hc[pix] = (_Float16)hv;
                oq[pix] = hv * inv + bnb;
            }
        }

        // ---- release: drain h stores, then publish step completion ----
        if (t < 15) {
            __threadfence();
            __syncthreads();                   // S2: all waves drained + fenced
            if (tid == 0)
                __hip_atomic_store(&fb[s], t + 1, __ATOMIC_RELEASE, __HIP_MEMORY_SCOPE_AGENT);
        }
    }
}

// ---- Fallback (coop launch refused): round-2 fused step kernel, 347 µs class ----
__global__ __launch_bounds__(256, 2)
void lstm_step_k(const float* __restrict__ x, const _Float16* __restrict__ Wcx,
                 const _Float16* __restrict__ Wch, const float* __restrict__ bias,
                 const float* __restrict__ gamma_, const float* __restrict__ beta_,
                 const float* __restrict__ mmean, const float* __restrict__ mvar,
                 const _Float16* __restrict__ hprev, _Float16* __restrict__ hnext,
                 float* __restrict__ csw, float* __restrict__ out, int t)
{
    __shared__ _Float16 xp[100 * PSTR];
    __shared__ _Float16 hq_[100 * PSTR];

    const int tid  = threadIdx.x;
    const int lane = tid & 63;
    const int w    = tid >> 6;
    const int l15  = lane & 15, quad = lane >> 4;
    const int chg  = w & 1, mtg = w >> 1;
    const int b = blockIdx.x, tx = blockIdx.y, ty = blockIdx.z;
    const int px0 = tx * 8, py0 = ty * 8;
    const int tile = ty * 8 + tx;

    const float* xt = x + (((size_t)b * 16 + t) * 4096) * 32;
    for (int i = tid; i < 400; i += 256) {
        const int pos = i >> 2, q = i & 3;
        const int row = pos / 10, col = pos - row * 10;
        const int gy = py0 + row - 1, gx = px0 + col - 1;
        half8 hv = {0, 0, 0, 0, 0, 0, 0, 0};
        if ((unsigned)gy < 64u && (unsigned)gx < 64u) {
            const float* sp = xt + ((size_t)(gy * 64 + gx)) * 32 + q * 8;
            const float4 v0 = *(const float4*)sp;
            const float4 v1 = *(const float4*)(sp + 4);
            hv = (half8){(_Float16)v0.x, (_Float16)v0.y, (_Float16)v0.z, (_Float16)v0.w,
                         (_Float16)v1.x, (_Float16)v1.y, (_Float16)v1.z, (_Float16)v1.w};
        }
        *(half8*)&xp[pos * PSTR + q * 8] = hv;
    }
    if (t > 0) {
        const _Float16* hb = hprev + (size_t)b * 4096 * 32;
        for (int i = tid; i < 400; i += 256) {
            const int pos = i >> 2, q = i & 3;
            const int row = pos / 10, col = pos - row * 10;
            const int gy = py0 + row - 1, gx = px0 + col - 1;
            half8 hv = {0, 0, 0, 0, 0, 0, 0, 0};
            if ((unsigned)gy < 64u && (unsigned)gx < 64u)
                hv = *(const half8*)(hb + ((size_t)(gy * 64 + gx)) * 32 + q * 8);
            *(half8*)&hq_[pos * PSTR + q * 8] = hv;
        }
    }
    __syncthreads();

    const int f = chg * 16 + l15;
    float bi[4];
    #pragma unroll
    for (int nt = 0; nt < 4; ++nt) bi[nt] = bias[nt * 32 + f];
    const float inv = gamma_[f] * rsqrtf(mvar[f] + 1e-3f);
    const float bnb = beta_[f] - mmean[f] * inv;

    f32x4 acc[2][4];
    #pragma unroll
    for (int mt = 0; mt < 2; ++mt)
        #pragma unroll
        for (int nt = 0; nt < 4; ++nt)
            acc[mt][nt] = (f32x4){bi[nt], bi[nt], bi[nt], bi[nt]};

    const int pbase = ((mtg * 4 + (l15 >> 3)) * 10 + (l15 & 7)) * PSTR + quad * 8;
    const _Float16* wbx = Wcx + (chg * 16 + l15) * 32 + quad * 8;

    #pragma unroll
    for (int tap = 0; tap < 9; ++tap) {
        const int ky = tap / 3, kx = tap - ky * 3;
        const half8 a0 = *(const half8*)&xp[pbase + (ky * 10 + kx) * PSTR];
        const half8 a1 = *(const half8*)&xp[pbase + (ky * 10 + kx + 20) * PSTR];
        #pragma unroll
        for (int nt = 0; nt < 4; ++nt) {
            const half8 bf = *(const half8*)(wbx + tap * 4096 + nt * 1024);
            acc[0][nt] = __builtin_amdgcn_mfma_f32_16x16x32_f16(a0, bf, acc[0][nt], 0, 0, 0);
            acc[1][nt] = __builtin_amdgcn_mfma_f32_16x16x32_f16(a1, bf, acc[1][nt], 0, 0, 0);
        }
    }
    if (t > 0) {
        const _Float16* wbh = Wch + (chg * 16 + l15) * 32 + quad * 8;
        #pragma unroll
        for (int tap = 0; tap < 9; ++tap) {
            const int ky = tap / 3, kx = tap - ky * 3;
            const half8 a0 = *(const half8*)&hq_[pbase + (ky * 10 + kx) * PSTR];
            const half8 a1 = *(const half8*)&hq_[pbase + (ky * 10 + kx + 20) * PSTR];
            #pragma unroll
            for (int nt = 0; nt < 4; ++nt) {
                const half8 bf = *(const half8*)(wbh + tap * 4096 + nt * 1024);
                acc[0][nt] = __builtin_amdgcn_mfma_f32_16x16x32_f16(a0, bf, acc[0][nt], 0, 0, 0);
                acc[1][nt] = __builtin_amdgcn_mfma_f32_16x16x32_f16(a1, bf, acc[1][nt], 0, 0, 0);
            }
        }
    }

    float* cp = csw + (((size_t)b * 64 + tile) * 256 + tid) * 8;
    f32x4 c0 = (f32x4){0.f, 0.f, 0.f, 0.f};
    f32x4 c1 = (f32x4){0.f, 0.f, 0.f, 0.f};
    if (t > 0) {
        c0 = *(const f32x4*)cp;
        c1 = *(const f32x4*)(cp + 4);
    }

    _Float16* hqn = hnext + (size_t)b * 4096 * 32;
    float* oq = out + (((size_t)b * 16 + t) * 4096) * 32;
    #pragma unroll
    for (int mt = 0; mt < 2; ++mt) {
        #pragma unroll
        for (int r = 0; r < 4; ++r) {
            const int px = (mtg * 2 + mt) * 16 + quad * 4 + r;
            const int gy = py0 + (px >> 3), gx = px0 + (px & 7);
            const float gi = acc[mt][0][r];
            const float gf = acc[mt][1][r];
            const float gc = acc[mt][2][r];
            const float go = acc[mt][3][r];
            const float co = mt ? c1[r] : c0[r];
            const float cn = hsig(gf) * co + hsig(gi) * fast_tanh(gc);
            const float hv = hsig(go) * fast_tanh(cn);
            if (mt) c1[r] = cn; else c0[r] = cn;
            const size_t pix = ((size_t)(gy * 64 + gx)) * 32 + f;
            hqn[pix] = (_Float16)hv;
            oq[pix] = hv * inv + bnb;
        }
    }
    *(f32x4*)cp       = c0;
    *(f32x4*)(cp + 4) = c1;
}

extern "C" void kernel_launch(void* const* d_in, const int* in_sizes, int n_in,
                              void* d_out, int out_size, void* d_ws, size_t ws_size,
                              hipStream_t stream)
{
    const float* x      = (const float*)d_in[0];
    const float* Wx     = (const float*)d_in[1];
    const float* Wh     = (const float*)d_in[2];
    const float* bias   = (const float*)d_in[3];
    const float* gamma_ = (const float*)d_in[4];
    const float* beta_  = (const float*)d_in[5];
    const float* mmean  = (const float*)d_in[6];
    const float* mvar   = (const float*)d_in[7];
    float* out = (float*)d_out;

    // ws: [h0 2MB][h1 2MB][csw 4MB (fallback)][Wcx 72KB][Wch 72KB][flags 1KB]
    char* wsb = (char*)d_ws;
    _Float16* h0    = (_Float16*)(wsb);
    _Float16* h1    = (_Float16*)(wsb + (1 << 21));
    float*    csw   = (float*)(wsb + (1 << 22));
    _Float16* Wcx   = (_Float16*)(wsb + (1 << 23));
    _Float16* Wch   = (_Float16*)(wsb + (1 << 23) + 73728);
    int*      flags = (int*)(wsb + (1 << 23) + 147456);

    hipMemsetAsync(flags, 0, 8 * 32 * sizeof(int), stream);
    prep_w<<<dim3(576), dim3(128), 0, stream>>>(Wx, Wh, Wcx, Wch);

    void* args[] = {(void*)&x, (void*)&Wcx, (void*)&Wch, (void*)&bias,
                    (void*)&gamma_, (void*)&beta_, (void*)&mmean, (void*)&mvar,
                    (void*)&h0, (void*)&h1, (void*)&flags, (void*)&out};
    hipError_t e = hipLaunchCooperativeKernel((void*)convlstm_pipe, dim3(8, 32),
                                              dim3(512), args, 0, stream);
    if (e != hipSuccess) {
        // Fallback: 16 sequential fused-step launches (round-2 path).
        _Float16* hpr = h0;
        _Float16* hnx = h1;
        for (int t = 0; t < 16; ++t) {
            lstm_step_k<<<dim3(8, 8, 8), 256, 0, stream>>>(
                x, Wcx, Wch, bias, gamma_, beta_, mmean, mvar, hpr, hnx, csw, out, t);
            _Float16* tmp = hpr; hpr = hnx; hnx = tmp;
        }
    }
}

// Round 7
// 293.005 us; speedup vs baseline: 7.0798x; 7.0798x over previous
//
#include <hip/hip_runtime.h>
#include <math.h>

// LDS geometry
#define PSTR 40            // fp16 patch cell stride: 80 B
#define GSTR 35            // gate-exchange row stride (floats; odd -> 2-way-free reads)
#define GPL  (64 * GSTR)   // one gate plane: 64 px x GSTR floats

typedef _Float16 half8 __attribute__((ext_vector_type(8)));
typedef float    f32x4 __attribute__((ext_vector_type(4)));

__device__ __forceinline__ float fast_tanh(float v) {
    float e = __expf(2.f * v);
    return 1.f - 2.f / (e + 1.f);
}
__device__ __forceinline__ float hsig(float v) {
    return fminf(fmaxf(0.2f * v + 0.5f, 0.f), 1.f);
}

// Pack weights: Wcx[tap][n][ci<32] from Wx[tap][ci][n]; Wch[tap][n][ci] from Wh[tap][ci][n]
__global__ void prep_w(const float* __restrict__ Wx, const float* __restrict__ Wh,
                       _Float16* __restrict__ Wcx, _Float16* __restrict__ Wch) {
    const int k = blockIdx.x;      // 0..575 = tap*64 + ci
    const int n = threadIdx.x;     // 0..127
    const int tap = k >> 6, ci = k & 63;
    if (ci < 32) Wcx[(tap * 128 + n) * 32 + ci]        = (_Float16)Wx[(tap * 32 + ci) * 128 + n];
    else         Wch[(tap * 128 + n) * 32 + (ci - 32)] = (_Float16)Wh[(tap * 32 + (ci - 32)) * 128 + n];
}

// One fused timestep per launch. N-split waves: wave w (0..3) computes GATE w for all
// 64 px of the 8x8 tile (4 m-tiles x 2 n-tiles of 16). B-frag loads per wave: 9 taps x
// 2 ntl x 2 convs = 36 KB (vs 144 KB for the chg-split layout) -> 4x less L1 traffic.
// Gates exchanged via padded LDS (glds[gate][px][f]); epilogue thread (px=tid>>2,
// f0=(tid&3)*8) does LSTM+BN with fully coalesced h/c/out writes.
// Grid (8,8,8): blockIdx.x = batch (XCD-local halo reads); launch boundary = coherence.
__global__ __launch_bounds__(256, 2)
void lstm_step_k(const float* __restrict__ x, const _Float16* __restrict__ Wcx,
                 const _Float16* __restrict__ Wch, const float* __restrict__ bias,
                 const float* __restrict__ gamma_, const float* __restrict__ beta_,
                 const float* __restrict__ mmean, const float* __restrict__ mvar,
                 const _Float16* __restrict__ hprev, _Float16* __restrict__ hnext,
                 float* __restrict__ csw, float* __restrict__ out, int t)
{
    __shared__ _Float16 xp[100 * PSTR];   // 8 KB: 10x10 halo x 32 x-ch
    __shared__ _Float16 hp[100 * PSTR];   // 8 KB: 10x10 halo x 32 h-ch
    __shared__ float    glds[4 * GPL];    // 35 KB: gate exchange [gate][px][f]

    const int tid  = threadIdx.x;
    const int lane = tid & 63;
    const int w    = tid >> 6;            // wave index == gate (i,f,c,o)
    const int l15  = lane & 15, quad = lane >> 4;
    const int b = blockIdx.x, tx = blockIdx.y, ty = blockIdx.z;
    const int px0 = tx * 8, py0 = ty * 8;
    const int tile = ty * 8 + tx;

    // ---- stage x patch (fp32 -> fp16) and h patch (fp16) ----
    const float* xt = x + (((size_t)b * 16 + t) * 4096) * 32;
    for (int i = tid; i < 400; i += 256) {
        const int pos = i >> 2, q = i & 3;
        const int row = pos / 10, col = pos - row * 10;
        const int gy = py0 + row - 1, gx = px0 + col - 1;
        half8 hv = {0, 0, 0, 0, 0, 0, 0, 0};
        if ((unsigned)gy < 64u && (unsigned)gx < 64u) {
            const float* s = xt + ((size_t)(gy * 64 + gx)) * 32 + q * 8;
            const float4 v0 = *(const float4*)s;
            const float4 v1 = *(const float4*)(s + 4);
            hv = (half8){(_Float16)v0.x, (_Float16)v0.y, (_Float16)v0.z, (_Float16)v0.w,
                         (_Float16)v1.x, (_Float16)v1.y, (_Float16)v1.z, (_Float16)v1.w};
        }
        *(half8*)&xp[pos * PSTR + q * 8] = hv;
    }
    if (t > 0) {
        const _Float16* hb = hprev + (size_t)b * 4096 * 32;
        for (int i = tid; i < 400; i += 256) {
            const int pos = i >> 2, q = i & 3;
            const int row = pos / 10, col = pos - row * 10;
            const int gy = py0 + row - 1, gx = px0 + col - 1;
            half8 hv = {0, 0, 0, 0, 0, 0, 0, 0};
            if ((unsigned)gy < 64u && (unsigned)gx < 64u)
                hv = *(const half8*)(hb + ((size_t)(gy * 64 + gx)) * 32 + q * 8);
            *(half8*)&hp[pos * PSTR + q * 8] = hv;
        }
    }

    // bias for this wave's two 16-wide n-tiles: n = w*32 + ntl*16 + l15
    const float bi0 = bias[w * 32 + l15];
    const float bi1 = bias[w * 32 + 16 + l15];

    __syncthreads();

    // ---- MFMA: acc[mt][ntl], px = mt*16 + quad*4 + r, col = w*32 + ntl*16 + l15 ----
    f32x4 acc[4][2];
    #pragma unroll
    for (int mt = 0; mt < 4; ++mt) {
        acc[mt][0] = (f32x4){bi0, bi0, bi0, bi0};
        acc[mt][1] = (f32x4){bi1, bi1, bi1, bi1};
    }

    int pb[4];
    #pragma unroll
    for (int mt = 0; mt < 4; ++mt) {
        const int p = mt * 16 + l15;       // A-frag row: patch cell (1+(p>>3), 1+(p&7))
        pb[mt] = ((mt * 2 + (l15 >> 3)) * 10 + (l15 & 7)) * PSTR + quad * 8;
    }
    const _Float16* wbx = Wcx + ((size_t)(w * 32 + l15)) * 32 + quad * 8;
    const _Float16* wbh = Wch + ((size_t)(w * 32 + l15)) * 32 + quad * 8;

    #pragma unroll
    for (int tap = 0; tap < 9; ++tap) {
        const int ky = tap / 3, kx = tap - ky * 3;
        const int toff = (ky * 10 + kx) * PSTR;
        half8 a[4];
        #pragma unroll
        for (int mt = 0; mt < 4; ++mt) a[mt] = *(const half8*)&xp[pb[mt] + toff];
        #pragma unroll
        for (int ntl = 0; ntl < 2; ++ntl) {
            const half8 bf = *(const half8*)(wbx + tap * 4096 + ntl * 512);
            #pragma unroll
            for (int mt = 0; mt < 4; ++mt)
                acc[mt][ntl] = __builtin_amdgcn_mfma_f32_16x16x32_f16(a[mt], bf, acc[mt][ntl], 0, 0, 0);
        }
    }
    if (t > 0) {
        #pragma unroll
        for (int tap = 0; tap < 9; ++tap) {
            const int ky = tap / 3, kx = tap - ky * 3;
            const int toff = (ky * 10 + kx) * PSTR;
            half8 a[4];
            #pragma unroll
            for (int mt = 0; mt < 4; ++mt) a[mt] = *(const half8*)&hp[pb[mt] + toff];
            #pragma unroll
            for (int ntl = 0; ntl < 2; ++ntl) {
                const half8 bf = *(const half8*)(wbh + tap * 4096 + ntl * 512);
                #pragma unroll
                for (int mt = 0; mt < 4; ++mt)
                    acc[mt][ntl] = __builtin_amdgcn_mfma_f32_16x16x32_f16(a[mt], bf, acc[mt][ntl], 0, 0, 0);
            }
        }
    }

    // ---- write this wave's gate plane to LDS: glds[w][px][f] ----
    #pragma unroll
    for (int mt = 0; mt < 4; ++mt)
        #pragma unroll
        for (int ntl = 0; ntl < 2; ++ntl)
            #pragma unroll
            for (int r = 0; r < 4; ++r) {
                const int px = mt * 16 + quad * 4 + r;
                glds[w * GPL + px * GSTR + ntl * 16 + l15] = acc[mt][ntl][r];
            }

    __syncthreads();

    // ---- epilogue: thread owns (px = tid>>2, f = f0..f0+7), coalesced I/O ----
    const int pxt = tid >> 2, f0 = (tid & 3) * 8;
    const int gy = py0 + (pxt >> 3), gx = px0 + (pxt & 7);

    float gav[8], bev[8], mmv[8], mvv[8];
    *(float4*)&gav[0] = *(const float4*)&gamma_[f0];
    *(float4*)&gav[4] = *(const float4*)&gamma_[f0 + 4];
    *(float4*)&bev[0] = *(const float4*)&beta_[f0];
    *(float4*)&bev[4] = *(const float4*)&beta_[f0 + 4];
    *(float4*)&mmv[0] = *(const float4*)&mmean[f0];
    *(float4*)&mmv[4] = *(const float4*)&mmean[f0 + 4];
    *(float4*)&mvv[0] = *(const float4*)&mvar[f0];
    *(float4*)&mvv[4] = *(const float4*)&mvar[f0 + 4];

    float* cp = csw + (((size_t)b * 64 + tile) * 256 + tid) * 8;
    float cov[8];
    #pragma unroll
    for (int j = 0; j < 8; ++j) cov[j] = 0.f;
    if (t > 0) {
        *(f32x4*)&cov[0] = *(const f32x4*)cp;
        *(f32x4*)&cov[4] = *(const f32x4*)(cp + 4);
    }

    const int gb = pxt * GSTR + f0;
    half8 hv8;
    float ov[8], cnv[8];
    #pragma unroll
    for (int j = 0; j < 8; ++j) {
        const float gi = glds[0 * GPL + gb + j];
        const float gf = glds[1 * GPL + gb + j];
        const float gc = glds[2 * GPL + gb + j];
        const float go = glds[3 * GPL + gb + j];
        const float inv = gav[j] * rsqrtf(mvv[j] + 1e-3f);
        const float bnb = bev[j] - mmv[j] * inv;
        const float cn = hsig(gf) * cov[j] + hsig(gi) * fast_tanh(gc);
        const float hh = hsig(go) * fast_tanh(cn);
        cnv[j] = cn;
        hv8[j] = (_Float16)hh;
        ov[j] = hh * inv + bnb;
    }

    const size_t pix = ((size_t)(gy * 64 + gx)) * 32 + f0;
    _Float16* hq = hnext + (size_t)b * 4096 * 32;
    float* oq = out + (((size_t)b * 16 + t) * 4096) * 32;
    *(half8*)(hq + pix) = hv8;                    // 16 B coalesced
    *(float4*)(oq + pix)     = *(float4*)&ov[0];  // 2 x 16 B coalesced
    *(float4*)(oq + pix + 4) = *(float4*)&ov[4];
    *(f32x4*)cp       = *(f32x4*)&cnv[0];         // 2 x 16 B coalesced
    *(f32x4*)(cp + 4) = *(f32x4*)&cnv[4];
}

extern "C" void kernel_launch(void* const* d_in, const int* in_sizes, int n_in,
                              void* d_out, int out_size, void* d_ws, size_t ws_size,
                              hipStream_t stream)
{
    const float* x      = (const float*)d_in[0];
    const float* Wx     = (const float*)d_in[1];
    const float* Wh     = (const float*)d_in[2];
    const float* bias   = (const float*)d_in[3];
    const float* gamma_ = (const float*)d_in[4];
    const float* beta_  = (const float*)d_in[5];
    const float* mmean  = (const float*)d_in[6];
    const float* mvar   = (const float*)d_in[7];
    float* out = (float*)d_out;

    // ws: [h0 2MB][h1 2MB][csw 4MB][Wcx 72KB][Wch 72KB]
    char* wsb = (char*)d_ws;
    _Float16* h0  = (_Float16*)(wsb);
    _Float16* h1  = (_Float16*)(wsb + (1 << 21));
    float*    csw = (float*)(wsb + (1 << 22));
    _Float16* Wcx = (_Float16*)(wsb + (1 << 23));
    _Float16* Wch = (_Float16*)(wsb + (1 << 23) + 73728);

    prep_w<<<dim3(576), dim3(128), 0, stream>>>(Wx, Wh, Wcx, Wch);

    // 16 fused-step launches. No memset: t=0 skips h-conv and starts c=0.
    _Float16* hpr = h0;
    _Float16* hnx = h1;
    for (int t = 0; t < 16; ++t) {
        lstm_step_k<<<dim3(8, 8, 8), 256, 0, stream>>>(
            x, Wcx, Wch, bias, gamma_, beta_, mmean, mvar, hpr, hnx, csw, out, t);
        _Float16* tmp = hpr; hpr = hnx; hnx = tmp;
    }
}